// Round 3
// baseline (1365.251 us; speedup 1.0000x reference)
//
#include <hip/hip_runtime.h>

#define N_NODES 200000
#define F_IN 128
#define HID 16
#define SHIFT 7
#define BKT_NODES 128                 // 1 << SHIFT
#define NB 1563                       // ceil(N_NODES / 128)
#define NBLK 256                      // hist/partition grid size
#define BLKT 512                      // hist/partition block threads
#define M_SCAN (NB * NBLK)            // 400128 (divisible by 256)

// ---------------- Stage 1: h = x @ W1  ([N,128] @ [128,16]) ----------------
__global__ __launch_bounds__(256) void gemm1_kernel(const float* __restrict__ x,
                                                    const float* __restrict__ W1,
                                                    float* __restrict__ h) {
    __shared__ float w[F_IN * HID];  // 8 KB
    int tid = threadIdx.x;
    for (int i = tid; i < F_IN * HID; i += 256) w[i] = W1[i];
    __syncthreads();

    int row = blockIdx.x * 256 + tid;
    if (row >= N_NODES) return;

    float acc[HID];
#pragma unroll
    for (int j = 0; j < HID; j++) acc[j] = 0.f;

    const float4* xr = reinterpret_cast<const float4*>(x + (size_t)row * F_IN);
#pragma unroll 4
    for (int k4 = 0; k4 < F_IN / 4; k4++) {
        float4 xv = xr[k4];
        const float* wr = &w[k4 * 4 * HID];
#pragma unroll
        for (int j = 0; j < HID; j++) acc[j] += xv.x * wr[j];
#pragma unroll
        for (int j = 0; j < HID; j++) acc[j] += xv.y * wr[HID + j];
#pragma unroll
        for (int j = 0; j < HID; j++) acc[j] += xv.z * wr[2 * HID + j];
#pragma unroll
        for (int j = 0; j < HID; j++) acc[j] += xv.w * wr[3 * HID + j];
    }

    float4* hr = reinterpret_cast<float4*>(h + (size_t)row * HID);
#pragma unroll
    for (int q = 0; q < HID / 4; q++)
        hr[q] = make_float4(acc[4 * q], acc[4 * q + 1], acc[4 * q + 2], acc[4 * q + 3]);
}

// ---------------- Bucket histogram: hist[b][blk] -----------------------------
__global__ __launch_bounds__(BLKT) void hist_kernel(const int* __restrict__ dst,
                                                    int* __restrict__ hist,
                                                    int n_edges, int chunk) {
    __shared__ int hc[NB];  // 6.3 KB
    int t = threadIdx.x, blk = blockIdx.x;
    for (int i = t; i < NB; i += BLKT) hc[i] = 0;
    __syncthreads();
    int e0 = blk * chunk;
    int e1 = e0 + chunk; if (e1 > n_edges) e1 = n_edges;
    for (int e = e0 + t; e < e1; e += BLKT)
        atomicAdd(&hc[dst[e] >> SHIFT], 1);
    __syncthreads();
    for (int b = t; b < NB; b += BLKT) hist[b * NBLK + blk] = hc[b];
}

// ---------------- 3-level exclusive scan over M_SCAN elements ----------------
__global__ __launch_bounds__(256) void scan1_kernel(const int* __restrict__ in,
                                                    int* __restrict__ out,
                                                    int* __restrict__ bsum, int n) {
    __shared__ int s[256];
    int t = threadIdx.x, i = blockIdx.x * 256 + t;
    int v = (i < n) ? in[i] : 0;
    s[t] = v; __syncthreads();
    for (int off = 1; off < 256; off <<= 1) {
        int u = (t >= off) ? s[t - off] : 0; __syncthreads();
        s[t] += u; __syncthreads();
    }
    if (i < n) out[i] = s[t] - v;  // block-local exclusive
    if (t == 255) bsum[blockIdx.x] = s[255];
}

// sequential-chunk exclusive scan of nb block sums, single block
__global__ __launch_bounds__(256) void scan2_kernel(int* __restrict__ bsum, int nb) {
    __shared__ int s[256];
    __shared__ int carry;
    int t = threadIdx.x;
    if (t == 0) carry = 0;
    __syncthreads();
    for (int base = 0; base < nb; base += 256) {
        int v = (base + t < nb) ? bsum[base + t] : 0;
        s[t] = v; __syncthreads();
        for (int off = 1; off < 256; off <<= 1) {
            int u = (t >= off) ? s[t - off] : 0; __syncthreads();
            s[t] += u; __syncthreads();
        }
        if (base + t < nb) bsum[base + t] = carry + s[t] - v;  // exclusive
        __syncthreads();
        if (t == 0) carry += s[255];
        __syncthreads();
    }
}

__global__ __launch_bounds__(256) void scan3_kernel(int* __restrict__ out,
                                                    const int* __restrict__ bsum,
                                                    int n, int total) {
    int i = blockIdx.x * 256 + threadIdx.x;
    if (i < n) out[i] += bsum[blockIdx.x];
    if (i == 0) out[n] = total;
}

// ---------------- Partition: bucket-grouped records, no global atomics -------
// record: {src | local_dst<<18, weight_bits}
__global__ __launch_bounds__(BLKT) void partition_kernel(const int* __restrict__ src,
                                                         const int* __restrict__ dst,
                                                         const float* __restrict__ ew,
                                                         const int* __restrict__ scanned,
                                                         int2* __restrict__ recs,
                                                         int n_edges, int chunk) {
    __shared__ int cur[NB];
    int t = threadIdx.x, blk = blockIdx.x;
    for (int b = t; b < NB; b += BLKT) cur[b] = scanned[b * NBLK + blk];
    __syncthreads();
    int e0 = blk * chunk;
    int e1 = e0 + chunk; if (e1 > n_edges) e1 = n_edges;
    for (int e = e0 + t; e < e1; e += BLKT) {
        int d = dst[e];
        int b = d >> SHIFT;
        int pos = atomicAdd(&cur[b], 1);  // LDS atomic, block-private range
        recs[pos] = make_int2(src[e] | ((d & (BKT_NODES - 1)) << 18),
                              __float_as_int(ew[e]));
    }
}

// ---------------- Aggregation per bucket, LDS accumulator --------------------
// layer 1: h2 = relu(agg + b1) @ W2
__global__ __launch_bounds__(256) void agg_mid_kernel(const float* __restrict__ h,
                                                      const int* __restrict__ scanned,
                                                      const int2* __restrict__ recs,
                                                      const float* __restrict__ b1,
                                                      const float* __restrict__ W2,
                                                      float* __restrict__ h2) {
    __shared__ float acc[BKT_NODES * HID];  // 8 KB
    __shared__ float wm[HID * HID];
    __shared__ float bs[HID];
    int t = threadIdx.x, bkt = blockIdx.x;
    for (int i = t; i < BKT_NODES * HID; i += 256) acc[i] = 0.f;
    if (t < HID * HID) wm[t] = W2[t];
    if (t < HID) bs[t] = b1[t];
    __syncthreads();

    int beg = scanned[bkt * NBLK];
    int end = scanned[(bkt + 1) * NBLK];
    int slot = t >> 2, q = t & 3;
    for (int p = beg + slot; p < end; p += 64) {
        int2 r = recs[p];
        int s = r.x & 0x3FFFF;
        int ld = ((unsigned)r.x) >> 18;
        float w = __int_as_float(r.y);
        float4 hv = *reinterpret_cast<const float4*>(h + (size_t)s * HID + q * 4);
        float* a = &acc[ld * HID + q * 4];
        atomicAdd(&a[0], hv.x * w);
        atomicAdd(&a[1], hv.y * w);
        atomicAdd(&a[2], hv.z * w);
        atomicAdd(&a[3], hv.w * w);
    }
    __syncthreads();

    int base = bkt * BKT_NODES;
    for (int i = t; i < BKT_NODES * HID; i += 256) {
        int n = i >> 4, f = i & 15;
        int node = base + n;
        if (node >= N_NODES) break;
        float sum = 0.f;
#pragma unroll
        for (int k = 0; k < HID; k++)
            sum += fmaxf(acc[n * HID + k] + bs[k], 0.f) * wm[k * HID + f];
        h2[(size_t)node * HID + f] = sum;
    }
}

// layer 2: out = relu(agg + b2) @ Wd + bd
__global__ __launch_bounds__(256) void agg_final_kernel(const float* __restrict__ h2,
                                                        const int* __restrict__ scanned,
                                                        const int2* __restrict__ recs,
                                                        const float* __restrict__ b2,
                                                        const float* __restrict__ Wd,
                                                        const float* __restrict__ bd,
                                                        float* __restrict__ out) {
    __shared__ float acc[BKT_NODES * HID];
    __shared__ float wd[HID];
    __shared__ float bs[HID];
    __shared__ float bdv;
    int t = threadIdx.x, bkt = blockIdx.x;
    for (int i = t; i < BKT_NODES * HID; i += 256) acc[i] = 0.f;
    if (t < HID) { wd[t] = Wd[t]; bs[t] = b2[t]; }
    if (t == 0) bdv = bd[0];
    __syncthreads();

    int beg = scanned[bkt * NBLK];
    int end = scanned[(bkt + 1) * NBLK];
    int slot = t >> 2, q = t & 3;
    for (int p = beg + slot; p < end; p += 64) {
        int2 r = recs[p];
        int s = r.x & 0x3FFFF;
        int ld = ((unsigned)r.x) >> 18;
        float w = __int_as_float(r.y);
        float4 hv = *reinterpret_cast<const float4*>(h2 + (size_t)s * HID + q * 4);
        float* a = &acc[ld * HID + q * 4];
        atomicAdd(&a[0], hv.x * w);
        atomicAdd(&a[1], hv.y * w);
        atomicAdd(&a[2], hv.z * w);
        atomicAdd(&a[3], hv.w * w);
    }
    __syncthreads();

    int node = bkt * BKT_NODES + t;
    if (t < BKT_NODES && node < N_NODES) {
        float s = bdv;
#pragma unroll
        for (int k = 0; k < HID; k++)
            s += fmaxf(acc[t * HID + k] + bs[k], 0.f) * wd[k];
        out[node] = s;
    }
}

// =================== Fallback path (R1): atomic scatter ====================
__global__ __launch_bounds__(256) void scatter_kernel(const float* __restrict__ h,
                                                      const int* __restrict__ src,
                                                      const int* __restrict__ dst,
                                                      const float* __restrict__ ew,
                                                      float* __restrict__ agg,
                                                      int n_edges) {
    long long idx = (long long)blockIdx.x * 256 + threadIdx.x;
    long long total = (long long)n_edges * HID;
    if (idx >= total) return;
    int e = (int)(idx >> 4);
    int j = (int)(idx & (HID - 1));
    float val = h[(size_t)src[e] * HID + j] * ew[e];
    atomicAdd(&agg[(size_t)dst[e] * HID + j], val);
}

__global__ __launch_bounds__(256) void gemm2_kernel(const float* __restrict__ agg,
                                                    const float* __restrict__ b1,
                                                    const float* __restrict__ W2,
                                                    float* __restrict__ h2) {
    __shared__ float w[HID * HID];
    __shared__ float bias[HID];
    int tid = threadIdx.x;
    if (tid < HID * HID) w[tid] = W2[tid];
    if (tid < HID) bias[tid] = b1[tid];
    __syncthreads();
    int row = blockIdx.x * 256 + tid;
    if (row >= N_NODES) return;
    float hv[HID];
    const float4* ar = reinterpret_cast<const float4*>(agg + (size_t)row * HID);
#pragma unroll
    for (int q = 0; q < 4; q++) {
        float4 v = ar[q];
        hv[4 * q + 0] = fmaxf(v.x + bias[4 * q + 0], 0.f);
        hv[4 * q + 1] = fmaxf(v.y + bias[4 * q + 1], 0.f);
        hv[4 * q + 2] = fmaxf(v.z + bias[4 * q + 2], 0.f);
        hv[4 * q + 3] = fmaxf(v.w + bias[4 * q + 3], 0.f);
    }
    float acc[HID];
#pragma unroll
    for (int j = 0; j < HID; j++) acc[j] = 0.f;
#pragma unroll
    for (int k = 0; k < HID; k++) {
        float hk = hv[k];
#pragma unroll
        for (int j = 0; j < HID; j++) acc[j] += hk * w[k * HID + j];
    }
    float4* hr = reinterpret_cast<float4*>(h2 + (size_t)row * HID);
#pragma unroll
    for (int q = 0; q < 4; q++)
        hr[q] = make_float4(acc[4 * q], acc[4 * q + 1], acc[4 * q + 2], acc[4 * q + 3]);
}

__global__ __launch_bounds__(256) void final_kernel(const float* __restrict__ agg,
                                                    const float* __restrict__ b2,
                                                    const float* __restrict__ Wd,
                                                    const float* __restrict__ bd,
                                                    float* __restrict__ out) {
    __shared__ float wd[HID];
    __shared__ float bias[HID];
    __shared__ float bdv;
    int tid = threadIdx.x;
    if (tid < HID) { wd[tid] = Wd[tid]; bias[tid] = b2[tid]; }
    if (tid == 0) bdv = bd[0];
    __syncthreads();
    int row = blockIdx.x * 256 + tid;
    if (row >= N_NODES) return;
    const float4* ar = reinterpret_cast<const float4*>(agg + (size_t)row * HID);
    float acc = bdv;
#pragma unroll
    for (int q = 0; q < 4; q++) {
        float4 v = ar[q];
        acc += fmaxf(v.x + bias[4 * q + 0], 0.f) * wd[4 * q + 0];
        acc += fmaxf(v.y + bias[4 * q + 1], 0.f) * wd[4 * q + 1];
        acc += fmaxf(v.z + bias[4 * q + 2], 0.f) * wd[4 * q + 2];
        acc += fmaxf(v.w + bias[4 * q + 3], 0.f) * wd[4 * q + 3];
    }
    out[row] = acc;
}

extern "C" void kernel_launch(void* const* d_in, const int* in_sizes, int n_in,
                              void* d_out, int out_size, void* d_ws, size_t ws_size,
                              hipStream_t stream) {
    const float* x    = (const float*)d_in[0];
    const int*   esrc = (const int*)d_in[1];
    const int*   edst = (const int*)d_in[2];
    const float* ew   = (const float*)d_in[3];
    const float* W1   = (const float*)d_in[4];
    const float* b1   = (const float*)d_in[5];
    const float* W2   = (const float*)d_in[6];
    const float* b2   = (const float*)d_in[7];
    const float* Wd   = (const float*)d_in[8];
    const float* bd   = (const float*)d_in[9];
    float* out = (float*)d_out;

    int n_edges = in_sizes[1];
    int num_node_blocks = (N_NODES + 255) / 256;

    // ---- workspace layout ----
    size_t node_buf = (size_t)N_NODES * HID * sizeof(float);   // 12.8 MB
    size_t hist_bytes = (size_t)M_SCAN * 4;                    // 1.6 MB
    size_t scan_bytes = ((size_t)M_SCAN + 1) * 4;              // 1.6 MB
    int scan_blocks = M_SCAN / 256;                            // 1563 exactly
    size_t bsum_bytes = (((size_t)scan_blocks * 4 + 15) / 16) * 16;
    size_t recs_bytes = (size_t)n_edges * 8;                   // 51.2 MB

    size_t needed = 2 * node_buf + hist_bytes + scan_bytes + bsum_bytes + recs_bytes;

    float* bufA = (float*)d_ws;
    float* bufB = (float*)((char*)d_ws + node_buf);

    if (ws_size >= needed && n_edges > 0) {
        char* p = (char*)d_ws + 2 * node_buf;
        int* hist    = (int*)p;  p += hist_bytes;
        int* scanned = (int*)p;  p += scan_bytes;
        int* bsum    = (int*)p;  p += bsum_bytes;
        int2* recs   = (int2*)p;

        int chunk = (n_edges + NBLK - 1) / NBLK;

        gemm1_kernel<<<num_node_blocks, 256, 0, stream>>>(x, W1, bufA);

        hist_kernel<<<NBLK, BLKT, 0, stream>>>(edst, hist, n_edges, chunk);
        scan1_kernel<<<scan_blocks, 256, 0, stream>>>(hist, scanned, bsum, M_SCAN);
        scan2_kernel<<<1, 256, 0, stream>>>(bsum, scan_blocks);
        scan3_kernel<<<scan_blocks, 256, 0, stream>>>(scanned, bsum, M_SCAN, n_edges);
        partition_kernel<<<NBLK, BLKT, 0, stream>>>(esrc, edst, ew, scanned, recs,
                                                    n_edges, chunk);

        agg_mid_kernel<<<NB, 256, 0, stream>>>(bufA, scanned, recs, b1, W2, bufB);
        agg_final_kernel<<<NB, 256, 0, stream>>>(bufB, scanned, recs, b2, Wd, bd, out);
    } else {
        // Fallback: R1 atomic path (needs only 2 node buffers)
        long long scatter_work = (long long)n_edges * HID;
        int scatter_blocks = (int)((scatter_work + 255) / 256);
        gemm1_kernel<<<num_node_blocks, 256, 0, stream>>>(x, W1, bufA);
        hipMemsetAsync(bufB, 0, node_buf, stream);
        scatter_kernel<<<scatter_blocks, 256, 0, stream>>>(bufA, esrc, edst, ew, bufB, n_edges);
        gemm2_kernel<<<num_node_blocks, 256, 0, stream>>>(bufB, b1, W2, bufA);
        hipMemsetAsync(bufB, 0, node_buf, stream);
        scatter_kernel<<<scatter_blocks, 256, 0, stream>>>(bufA, esrc, edst, ew, bufB, n_edges);
        final_kernel<<<num_node_blocks, 256, 0, stream>>>(bufB, b2, Wd, bd, out);
    }
}